// Round 2
// baseline (393.987 us; speedup 1.0000x reference)
//
#include <hip/hip_runtime.h>

// DetectionLoss: B=16, A=65536, T=32, C=21.
// R2: coalesced LDS-staged conf, counts-only u32 L1 histogram, per-anchor
// max-focal-bits filter so refine passes touch only O(k) anchors.
// Exact top-k sum via 3-level (12/12/8) radix select on focal float bits.

#define AN 65536
#define BN 16
#define TN 32
#define CN 21
#define NB1 4096

struct Accum { double pos_sum; double bbox_sum; double all_sum; unsigned num_pos; unsigned n_neg; };
struct Chain { double sumAbove; double topk; unsigned active; unsigned b1; unsigned b2; unsigned rem; };

// ---------- shared math (bit-identical across kernels: _rn intrinsics) ----------
__device__ __forceinline__ void softmax_row(const float* __restrict__ row, float* __restrict__ p) {
    float c[CN];
#pragma unroll
    for (int j = 0; j < CN; ++j) c[j] = row[j];
    float m = c[0];
#pragma unroll
    for (int j = 1; j < CN; ++j) m = fmaxf(m, c[j]);
    float s = 0.f;
#pragma unroll
    for (int j = 0; j < CN; ++j) { c[j] = __expf(__fsub_rn(c[j], m)); s = __fadd_rn(s, c[j]); }
    float inv = 1.0f / s;
#pragma unroll
    for (int j = 0; j < CN; ++j) p[j] = __fmul_rn(c[j], inv);
}

__device__ __forceinline__ float focal_cell(float p, bool cellpos) {
    float pt = cellpos ? p : __fsub_rn(1.0f, p);
    float af = cellpos ? 0.25f : 0.75f;
    float om = __fsub_rn(1.0f, pt);
    float lg = __logf(fmaxf(pt, 1e-6f));
    return __fmul_rn(__fmul_rn(__fmul_rn(-af, om), om), lg);
}

__device__ __forceinline__ unsigned focal_bits(float fo) {
    unsigned bits = __float_as_uint(fo);
    if (bits == 0x80000000u) bits = 0u;  // canonicalize -0.0
    return bits;
}

// ---------- kernel A: matching ----------
__global__ __launch_bounds__(256) void match_kernel(
    const float4* __restrict__ anchors, const float4* __restrict__ tboxes,
    float* __restrict__ max_iou, unsigned char* __restrict__ best_t,
    unsigned long long* __restrict__ gbest)
{
    __shared__ float4 tbS[TN];
    __shared__ float iouS[256 * (TN + 1)];
    __shared__ float pbV[TN][8];
    __shared__ int   pbA[TN][8];
    int b = blockIdx.y, tid = threadIdx.x;
    int a = blockIdx.x * 256 + tid;
    if (tid < TN) tbS[tid] = tboxes[b * TN + tid];
    __syncthreads();
    float4 ab = anchors[a];
    float a1 = (ab.z - ab.x) * (ab.w - ab.y);
    float best = -1.0f; int bt = 0;
#pragma unroll
    for (int t = 0; t < TN; ++t) {
        float4 t4 = tbS[t];
        float x1 = fmaxf(ab.x, t4.x), y1 = fmaxf(ab.y, t4.y);
        float x2 = fminf(ab.z, t4.z), y2 = fminf(ab.w, t4.w);
        float inter = fmaxf(x2 - x1, 0.f) * fmaxf(y2 - y1, 0.f);
        float a2 = (t4.z - t4.x) * (t4.w - t4.y);
        float iou = inter / (a1 + a2 - inter + 1e-6f);
        iouS[tid * (TN + 1) + t] = iou;
        if (iou > best) { best = iou; bt = t; }
    }
    max_iou[(size_t)b * AN + a] = best;
    best_t[(size_t)b * AN + a] = (unsigned char)bt;
    __syncthreads();
    {
        int t = tid >> 3, pp = tid & 7;
        float bv = -1.f; int ba = 0;
        for (int r = pp * 32; r < pp * 32 + 32; ++r) {
            float v = iouS[r * (TN + 1) + t];
            if (v > bv) { bv = v; ba = r; }
        }
        pbV[t][pp] = bv; pbA[t][pp] = ba;
    }
    __syncthreads();
    if (tid < TN) {
        float bv = -1.f; int ba = 0;
#pragma unroll
        for (int pp = 0; pp < 8; ++pp) {
            float v = pbV[tid][pp];
            if (v > bv) { bv = v; ba = pbA[tid][pp]; }
        }
        unsigned ga = blockIdx.x * 256 + (unsigned)ba;
        unsigned long long key =
            (((unsigned long long)__float_as_uint(bv)) << 32) | (unsigned long long)(unsigned)(~ga);
        atomicMax(&gbest[b * TN + tid], key);
    }
}

// ---------- kernel B: force-match overrides ----------
__global__ void force_kernel(const unsigned long long* __restrict__ gbest,
                             unsigned char* __restrict__ ovr)
{
    int i = blockIdx.x * blockDim.x + threadIdx.x;
    if (i < BN * TN) {
        unsigned long long key = gbest[i];
        unsigned ga = ~(unsigned)(key & 0xFFFFFFFFull);
        int b = i / TN;
        ovr[(size_t)b * AN + ga] = 1;
    }
}

// ---------- kernel C: focal, sums, L1 count-histogram, per-anchor max bits ----------
__global__ __launch_bounds__(256) void main_kernel(
    const float* __restrict__ conf, const float4* __restrict__ bboxp,
    const float4* __restrict__ tboxes, const int* __restrict__ tlabels,
    const float* __restrict__ max_iou, const unsigned char* __restrict__ best_t,
    const unsigned char* __restrict__ ovr,
    unsigned* __restrict__ cnt1, unsigned* __restrict__ maxb,
    Accum* __restrict__ acc)
{
    __shared__ float confS[256 * CN];        // 21504 B
    __shared__ unsigned h[NB1];              // 16384 B
    __shared__ float4 tbS[TN];
    __shared__ int tlS[TN];
    __shared__ float rF[3][4];
    __shared__ int rI[2][4];
    int b = blockIdx.y, tid = threadIdx.x;
    int a = blockIdx.x * 256 + tid;
    for (int i = tid; i < NB1; i += 256) h[i] = 0u;
    if (tid < TN) { tbS[tid] = tboxes[b * TN + tid]; tlS[tid] = tlabels[b * TN + tid]; }
    // coalesced staging: block's conf region is 5376 floats = 1344 float4, 16B-aligned
    {
        const float4* cp = (const float4*)(conf + ((size_t)b * AN + (size_t)blockIdx.x * 256) * CN);
        float4* cs = (float4*)confS;
        for (int i = tid; i < (256 * CN) / 4; i += 256) cs[i] = cp[i];
    }
    __syncthreads();

    size_t idx = (size_t)b * AN + a;
    float mi = max_iou[idx];
    bool ov = ovr[idx] != 0;
    bool posA = (mi >= 0.5f) || ov;
    bool negA = (mi < 0.4f) && !ov;
    int bt = best_t[idx];
    int label = posA ? tlS[bt] : -1;

    float p[CN];
    softmax_row(&confS[tid * CN], p);
    float fall = 0.f;
    unsigned mb = 0u;
#pragma unroll
    for (int j = 0; j < CN; ++j) {
        float fo = focal_cell(p[j], j == label);
        fall += fo;
        if (negA) {
            unsigned bits = focal_bits(fo);
            mb = max(mb, bits);
            atomicAdd(&h[bits >> 20], 1u);
        }
    }
    maxb[idx] = negA ? mb : 0u;

    float bper = 0.f;
    if (posA) {
        float4 b1 = bboxp[idx];
        float4 b2 = tbS[bt];
        float x1 = fmaxf(b1.x, b2.x), y1 = fmaxf(b1.y, b2.y);
        float x2 = fminf(b1.z, b2.z), y2 = fminf(b1.w, b2.w);
        float inter = fmaxf(x2 - x1, 0.f) * fmaxf(y2 - y1, 0.f);
        float a1 = (b1.z - b1.x) * (b1.w - b1.y);
        float a2 = (b2.z - b2.x) * (b2.w - b2.y);
        float un = a1 + a2 - inter;
        float iou = inter / (un + 1e-6f);
        float ex1 = fminf(b1.x, b2.x), ey1 = fminf(b1.y, b2.y);
        float ex2 = fmaxf(b1.z, b2.z), ey2 = fmaxf(b1.w, b2.w);
        float enc = (ex2 - ex1) * (ey2 - ey1);
        float giou = iou - (enc - un) / (enc + 1e-6f);
        float gl = 1.0f - giou;
        float l1 = 0.f, d, ad;
        d = b1.x - b2.x; ad = fabsf(d); l1 += (ad < 1.0f) ? (0.5f * d * d) : (ad - 0.5f);
        d = b1.y - b2.y; ad = fabsf(d); l1 += (ad < 1.0f) ? (0.5f * d * d) : (ad - 0.5f);
        d = b1.z - b2.z; ad = fabsf(d); l1 += (ad < 1.0f) ? (0.5f * d * d) : (ad - 0.5f);
        d = b1.w - b2.w; ad = fabsf(d); l1 += (ad < 1.0f) ? (0.5f * d * d) : (ad - 0.5f);
        l1 *= 0.25f;
        bper = gl + 0.5f * l1;
    }
    // block reduce
    float vall = fall, vpos = posA ? fall : 0.f, vb = bper;
    int inp = posA ? 1 : 0, inn = negA ? 1 : 0;
#pragma unroll
    for (int off = 32; off; off >>= 1) {
        vall += __shfl_down(vall, off, 64);
        vpos += __shfl_down(vpos, off, 64);
        vb   += __shfl_down(vb,   off, 64);
        inp  += __shfl_down(inp,  off, 64);
        inn  += __shfl_down(inn,  off, 64);
    }
    int wv = tid >> 6, ln = tid & 63;
    if (ln == 0) { rF[0][wv] = vall; rF[1][wv] = vpos; rF[2][wv] = vb; rI[0][wv] = inp; rI[1][wv] = inn; }
    __syncthreads();
    if (tid == 0) {
        float s0 = 0, s1 = 0, s2 = 0; int c0 = 0, c1 = 0;
        for (int w = 0; w < 4; ++w) { s0 += rF[0][w]; s1 += rF[1][w]; s2 += rF[2][w]; c0 += rI[0][w]; c1 += rI[1][w]; }
        atomicAdd(&acc[b].all_sum, (double)s0);
        atomicAdd(&acc[b].pos_sum, (double)s1);
        atomicAdd(&acc[b].bbox_sum, (double)s2);
        atomicAdd(&acc[b].num_pos, (unsigned)c0);
        atomicAdd(&acc[b].n_neg, (unsigned)c1);
    }
    for (int i = tid; i < NB1; i += 256) {
        unsigned v = h[i];
        if (v) atomicAdd(&cnt1[b * NB1 + i], v);
    }
}

// ---------- select level 1 (counts only) ----------
__global__ __launch_bounds__(256) void select1_kernel(
    const unsigned* __restrict__ cnt1, const Accum* __restrict__ acc,
    Chain* __restrict__ chains)
{
    int b = blockIdx.x, tid = threadIdx.x;
    Chain* ch = &chains[b];
    unsigned np = acc[b].num_pos, nn = acc[b].n_neg;
    unsigned k = (np > 0) ? min(3u * np, nn) : min(100u, nn);
    if (nn == 0 || k == 0) return;  // inactive, topk stays 0
    const unsigned* cnt = cnt1 + (size_t)b * NB1;
    unsigned lc[16], ccnt = 0;
#pragma unroll
    for (int i = 0; i < 16; ++i) { lc[i] = cnt[tid * 16 + i]; ccnt += lc[i]; }
    __shared__ unsigned scnt[256];
    scnt[tid] = ccnt;
    __syncthreads();
    for (int off = 1; off < 256; off <<= 1) {
        unsigned vc = (tid + off < 256) ? scnt[tid + off] : 0u;
        __syncthreads();
        scnt[tid] += vc;
        __syncthreads();
    }
    unsigned total = scnt[0];
    unsigned aboveCnt = (tid < 255) ? scnt[tid + 1] : 0u;
    unsigned r = min(k, total);
    if (r == 0) return;
    if (aboveCnt < r && aboveCnt + ccnt >= r) {
        unsigned acc2 = aboveCnt;
        for (int i = 15; i >= 0; --i) {
            unsigned bc = lc[i];
            if (acc2 + bc >= r) { ch->b1 = (unsigned)(tid * 16 + i); ch->rem = r - acc2; ch->active = 1; break; }
            acc2 += bc;
        }
    }
}

// ---------- refine level 2: exact sumAbove + L2 cnt/sum for boundary bin ----------
__global__ __launch_bounds__(256) void refine2_kernel(
    const float* __restrict__ conf, const float* __restrict__ max_iou,
    const unsigned char* __restrict__ ovr, const unsigned* __restrict__ maxb,
    Chain* __restrict__ chains,
    unsigned* __restrict__ cnt2, double* __restrict__ sum2)
{
    int b = blockIdx.y, tid = threadIdx.x;
    Chain* ch = &chains[b];
    if (!ch->active) return;
    unsigned b1 = ch->b1;
    unsigned thrBits = b1 << 20;
    int a = blockIdx.x * 256 + tid;
    size_t idx = (size_t)b * AN + a;
    unsigned mb = maxb[idx];
    float mi = max_iou[idx];
    bool q = (mb >= thrBits) && (mi < 0.4f) && (ovr[idx] == 0);
    __shared__ int any;
    if (tid == 0) any = 0;
    __syncthreads();
    if (q) any = 1;
    __syncthreads();
    if (!any) return;
    if (!q) return;
    float p[CN];
    softmax_row(conf + idx * CN, p);
    double sA = 0.0;
#pragma unroll
    for (int j = 0; j < CN; ++j) {
        float fo = focal_cell(p[j], false);
        unsigned bits = focal_bits(fo);
        unsigned hi = bits >> 20;
        if (hi > b1) sA += (double)fo;
        else if (hi == b1) {
            unsigned bin = (bits >> 8) & 0xFFFu;
            atomicAdd(&cnt2[b * NB1 + bin], 1u);
            atomicAdd(&sum2[b * NB1 + bin], (double)fo);
        }
    }
    if (sA != 0.0) atomicAdd(&ch->sumAbove, sA);
}

// ---------- select level 2 (counts + sums) ----------
__global__ __launch_bounds__(256) void select2_kernel(
    const unsigned* __restrict__ cnt2, const double* __restrict__ sum2,
    Chain* __restrict__ chains)
{
    int b = blockIdx.x, tid = threadIdx.x;
    Chain* ch = &chains[b];
    if (!ch->active) return;
    unsigned rem = ch->rem;
    const unsigned* cnt = cnt2 + (size_t)b * NB1;
    const double* sum = sum2 + (size_t)b * NB1;
    unsigned lc[16], ccnt = 0; double ls[16], csum = 0.0;
#pragma unroll
    for (int i = 0; i < 16; ++i) {
        lc[i] = cnt[tid * 16 + i]; ls[i] = sum[tid * 16 + i];
        ccnt += lc[i]; csum += ls[i];
    }
    __shared__ unsigned scnt[256];
    __shared__ double ssum[256];
    scnt[tid] = ccnt; ssum[tid] = csum;
    __syncthreads();
    for (int off = 1; off < 256; off <<= 1) {
        unsigned vc = 0; double vs = 0.0;
        if (tid + off < 256) { vc = scnt[tid + off]; vs = ssum[tid + off]; }
        __syncthreads();
        scnt[tid] += vc; ssum[tid] += vs;
        __syncthreads();
    }
    unsigned total = scnt[0];
    unsigned aboveCnt = (tid < 255) ? scnt[tid + 1] : 0u;
    double aboveSum = (tid < 255) ? ssum[tid + 1] : 0.0;
    unsigned r = min(rem, total);
    if (r == 0) return;
    if (aboveCnt < r && aboveCnt + ccnt >= r) {
        unsigned acc2 = aboveCnt; double asum = aboveSum;
        for (int i = 15; i >= 0; --i) {
            unsigned bc = lc[i];
            if (acc2 + bc >= r) {
                ch->b2 = (unsigned)(tid * 16 + i);
                ch->rem = r - acc2;
                ch->sumAbove += asum;
                break;
            }
            acc2 += bc; asum += ls[i];
        }
    }
}

// ---------- refine level 3 ----------
__global__ __launch_bounds__(256) void refine3_kernel(
    const float* __restrict__ conf, const float* __restrict__ max_iou,
    const unsigned char* __restrict__ ovr, const unsigned* __restrict__ maxb,
    const Chain* __restrict__ chains,
    unsigned* __restrict__ cnt3, double* __restrict__ sum3)
{
    int b = blockIdx.y, tid = threadIdx.x;
    const Chain* ch = &chains[b];
    if (!ch->active) return;
    unsigned b1 = ch->b1, b2 = ch->b2;
    unsigned thrBits = b1 << 20;
    int a = blockIdx.x * 256 + tid;
    size_t idx = (size_t)b * AN + a;
    unsigned mb = maxb[idx];
    float mi = max_iou[idx];
    bool q = (mb >= thrBits) && (mi < 0.4f) && (ovr[idx] == 0);
    __shared__ int any;
    if (tid == 0) any = 0;
    __syncthreads();
    if (q) any = 1;
    __syncthreads();
    if (!any) return;
    if (!q) return;
    float p[CN];
    softmax_row(conf + idx * CN, p);
#pragma unroll
    for (int j = 0; j < CN; ++j) {
        float fo = focal_cell(p[j], false);
        unsigned bits = focal_bits(fo);
        if ((bits >> 20) == b1 && ((bits >> 8) & 0xFFFu) == b2) {
            unsigned bin = bits & 0xFFu;
            atomicAdd(&cnt3[b * 256 + bin], 1u);
            atomicAdd(&sum3[b * 256 + bin], (double)fo);
        }
    }
}

// ---------- select level 3 (final) ----------
__global__ __launch_bounds__(256) void select3_kernel(
    const unsigned* __restrict__ cnt3, const double* __restrict__ sum3,
    Chain* __restrict__ chains)
{
    int b = blockIdx.x, tid = threadIdx.x;
    Chain* ch = &chains[b];
    if (!ch->active) return;
    unsigned rem = ch->rem;
    unsigned c = cnt3[b * 256 + tid];
    double s = sum3[b * 256 + tid];
    __shared__ unsigned scnt[256];
    __shared__ double ssum[256];
    scnt[tid] = c; ssum[tid] = s;
    __syncthreads();
    for (int off = 1; off < 256; off <<= 1) {
        unsigned vc = 0; double vs = 0.0;
        if (tid + off < 256) { vc = scnt[tid + off]; vs = ssum[tid + off]; }
        __syncthreads();
        scnt[tid] += vc; ssum[tid] += vs;
        __syncthreads();
    }
    unsigned total = scnt[0];
    unsigned aboveCnt = (tid < 255) ? scnt[tid + 1] : 0u;
    double aboveSum = (tid < 255) ? ssum[tid + 1] : 0.0;
    unsigned r = min(rem, total);
    if (r == 0) { if (tid == 0) ch->topk = ch->sumAbove; return; }
    if (aboveCnt < r && aboveCnt + c >= r) {
        unsigned vbits = (ch->b1 << 20) | (ch->b2 << 8) | (unsigned)tid;
        double v = (double)__uint_as_float(vbits);
        ch->topk = ch->sumAbove + aboveSum + (double)(r - aboveCnt) * v;
    }
}

// ---------- finalize ----------
__global__ void finalize_kernel(const Accum* __restrict__ acc,
                                const Chain* __restrict__ chains,
                                float* __restrict__ out)
{
    __shared__ double cl[BN], bl[BN];
    int t = threadIdx.x;
    if (t < BN) {
        unsigned np = acc[t].num_pos, nn = acc[t].n_neg;
        double pos_sum = acc[t].pos_sum, all_sum = acc[t].all_sum, bbox_sum = acc[t].bbox_sum;
        double conf;
        if (np > 0) {
            if (nn > 0) {
                unsigned k = min(3u * np, nn);
                conf = (pos_sum + chains[t].topk) / (double)(np + k);
            } else conf = pos_sum / (double)np;
        } else {
            if (nn > 0) {
                unsigned k2 = min(100u, nn);
                conf = chains[t].topk / (double)(k2 > 0 ? k2 : 1u);
            } else conf = all_sum / (double)((size_t)AN * CN);
        }
        cl[t] = conf;
        bl[t] = (np > 0) ? (bbox_sum / (double)np) : 0.0;
    }
    __syncthreads();
    if (t == 0) {
        double cs = 0, bs = 0;
        for (int i = 0; i < BN; ++i) { cs += cl[i]; bs += bl[i]; }
        cs /= BN; bs /= BN;
        out[0] = (float)(cs + bs);
        out[1] = (float)cs;
        out[2] = (float)bs;
    }
}

extern "C" void kernel_launch(void* const* d_in, const int* in_sizes, int n_in,
                              void* d_out, int out_size, void* d_ws, size_t ws_size,
                              hipStream_t stream)
{
    (void)in_sizes; (void)n_in; (void)out_size; (void)ws_size;
    const float*  conf    = (const float*)d_in[0];
    const float4* bboxp   = (const float4*)d_in[1];
    const float4* anchors = (const float4*)d_in[2];
    const float4* tboxes  = (const float4*)d_in[3];
    const int*    tlabels = (const int*)d_in[4];
    float* out = (float*)d_out;
    char* ws = (char*)d_ws;
    size_t off = 0;
    auto alloc = [&](size_t bytes) -> void* {
        void* p = (void*)(ws + off);
        off = (off + bytes + 255) & ~(size_t)255;
        return p;
    };
    float*              max_iou = (float*)alloc((size_t)BN * AN * 4);
    unsigned char*      bestt   = (unsigned char*)alloc((size_t)BN * AN);
    unsigned*           maxb    = (unsigned*)alloc((size_t)BN * AN * 4);
    size_t zstart = off;
    unsigned char*      ovr    = (unsigned char*)alloc((size_t)BN * AN);
    unsigned long long* gbest  = (unsigned long long*)alloc((size_t)BN * TN * 8);
    Accum*              acc    = (Accum*)alloc(BN * sizeof(Accum));
    Chain*              chains = (Chain*)alloc(BN * sizeof(Chain));
    unsigned* cnt1 = (unsigned*)alloc((size_t)BN * NB1 * 4);
    unsigned* cnt2 = (unsigned*)alloc((size_t)BN * NB1 * 4);
    double*   sum2 = (double*)alloc((size_t)BN * NB1 * 8);
    unsigned* cnt3 = (unsigned*)alloc((size_t)BN * 256 * 4);
    double*   sum3 = (double*)alloc((size_t)BN * 256 * 8);
    size_t zbytes = off - zstart;
    hipMemsetAsync(ws + zstart, 0, zbytes, stream);

    dim3 gridA(AN / 256, BN);
    match_kernel<<<gridA, 256, 0, stream>>>(anchors, tboxes, max_iou, bestt, gbest);
    force_kernel<<<1, 512, 0, stream>>>(gbest, ovr);
    main_kernel<<<gridA, 256, 0, stream>>>(conf, bboxp, tboxes, tlabels, max_iou, bestt, ovr,
                                           cnt1, maxb, acc);
    select1_kernel<<<BN, 256, 0, stream>>>(cnt1, acc, chains);
    refine2_kernel<<<gridA, 256, 0, stream>>>(conf, max_iou, ovr, maxb, chains, cnt2, sum2);
    select2_kernel<<<BN, 256, 0, stream>>>(cnt2, sum2, chains);
    refine3_kernel<<<gridA, 256, 0, stream>>>(conf, max_iou, ovr, maxb, chains, cnt3, sum3);
    select3_kernel<<<BN, 256, 0, stream>>>(cnt3, sum3, chains);
    finalize_kernel<<<1, 64, 0, stream>>>(acc, chains, out);
}